// Round 1
// baseline (197.375 us; speedup 1.0000x reference)
//
#include <hip/hip_runtime.h>
#include <hip/hip_bf16.h>

typedef __attribute__((ext_vector_type(4))) float f32x4;
typedef __attribute__((ext_vector_type(8))) short bf16x8;

// global -> LDS direct DMA, 16 B/lane. LDS dest = wave-uniform base + lane*16.
#define GLDS16(gp, lp) __builtin_amdgcn_global_load_lds( \
    (__attribute__((address_space(1))) void*)(void*)(gp), \
    (__attribute__((address_space(3))) void*)(lp), 16, 0, 0)

static constexpr int Mtot = 4 * 24 * 512;   // 49152 rows (b,h,n)
static constexpr int Ktot = 128 * 6;        // 768 = (C+8) features x (silu + 5 RBF)
static constexpr int Otot = 512;
static constexpr int Hh   = 24;
static constexpr int Cc   = 120;

__device__ inline unsigned short f2bf(float f) {
    __hip_bfloat16 h = __float2bfloat16(f);
    unsigned short u;
    __builtin_memcpy(&u, &h, 2);
    return u;
}

// Expand inputs into bf16 activation matrix A[M][768].
// One thread per (m, i): reads one scalar, writes 6 bf16 = 12 contiguous bytes.
__global__ __launch_bounds__(256) void prep_A(
        const float* __restrict__ x, const int* __restrict__ t_idx,
        const float* __restrict__ temb, unsigned int* __restrict__ A)
{
    int tid = blockIdx.x * 256 + threadIdx.x;   // tid = m*128 + i
    int i = tid & 127;
    int m = tid >> 7;
    int h = (m >> 9) % Hh;                      // m = ((b*H+h)*N+n), N=512
    float v;
    if (i < Cc) v = x[m * Cc + i];
    else        v = temb[t_idx[h] * 8 + (i - Cc)];
    float f[6];
    f[0] = v / (1.0f + __expf(-v));             // silu
    #pragma unroll
    for (int g = 0; g < 5; ++g) {               // grid = -1,-0.5,0,0.5,1 ; inv_h = 2
        float t2 = 2.0f * (v - (-1.0f + 0.5f * g));
        f[1 + g] = __expf(-t2 * t2);
    }
    A[tid * 3 + 0] = f2bf(f[0]) | ((unsigned)f2bf(f[1]) << 16);
    A[tid * 3 + 1] = f2bf(f[2]) | ((unsigned)f2bf(f[3]) << 16);
    A[tid * 3 + 2] = f2bf(f[4]) | ((unsigned)f2bf(f[5]) << 16);
}

// Pack [base_w | spline_w] -> bf16 Wt[O][768] (B^T layout, K-contiguous).
__global__ __launch_bounds__(256) void prep_W(
        const float* __restrict__ bw, const float* __restrict__ sw,
        unsigned int* __restrict__ Wt)
{
    int tid = blockIdx.x * 256 + threadIdx.x;   // tid = o*128 + i
    float f[6];
    f[0] = bw[tid];
    #pragma unroll
    for (int g = 0; g < 5; ++g) f[1 + g] = sw[tid * 5 + g];
    Wt[tid * 3 + 0] = f2bf(f[0]) | ((unsigned)f2bf(f[1]) << 16);
    Wt[tid * 3 + 1] = f2bf(f[2]) | ((unsigned)f2bf(f[3]) << 16);
    Wt[tid * 3 + 2] = f2bf(f[4]) | ((unsigned)f2bf(f[5]) << 16);
}

// C[M][512] = A[M][768] @ Wt[512][768]^T + bias.
// 128x128 block tile, BK=32, 4 waves (2x2), 4x4 16x16x32 bf16 MFMA frags/wave.
__global__ __launch_bounds__(256) void gemm_kan(
        const __hip_bfloat16* __restrict__ A,
        const __hip_bfloat16* __restrict__ W,
        const float* __restrict__ bias,
        float* __restrict__ out)
{
    __shared__ __hip_bfloat16 As[128 * 32];   // [row][k] row-major, 64 B rows
    __shared__ __hip_bfloat16 Bs[128 * 32];   // [col][k] row-major (W is B^T)
    const int t    = threadIdx.x;
    const int wave = t >> 6;
    const int lane = t & 63;
    const int m_base = blockIdx.x * 128;
    const int n_base = blockIdx.y * 128;
    const int wm = (wave >> 1) * 64;
    const int wn = (wave & 1) * 64;

    f32x4 acc[4][4] = {};

    // staging sources: per issue, thread t loads row (t>>2), 16B chunk (t&3)
    const __hip_bfloat16* ag0 = A + (long)(m_base +      (t >> 2)) * Ktot + (t & 3) * 8;
    const __hip_bfloat16* ag1 = A + (long)(m_base + 64 + (t >> 2)) * Ktot + (t & 3) * 8;
    const __hip_bfloat16* bg0 = W + (long)(n_base +      (t >> 2)) * Ktot + (t & 3) * 8;
    const __hip_bfloat16* bg1 = W + (long)(n_base + 64 + (t >> 2)) * Ktot + (t & 3) * 8;

    char* AsB = (char*)As;
    char* BsB = (char*)Bs;
    char* lA0 = AsB +        wave * 1024;     // wave-uniform LDS bases
    char* lA1 = AsB + 4096 + wave * 1024;
    char* lB0 = BsB +        wave * 1024;
    char* lB1 = BsB + 4096 + wave * 1024;

    // MFMA fragment LDS addresses: lane holds m=lane&15, k=(lane>>4)*8..+7
    const char* pa = AsB + (wm + (lane & 15)) * 64 + (lane >> 4) * 16;
    const char* pb = BsB + (wn + (lane & 15)) * 64 + (lane >> 4) * 16;

    for (int kt = 0; kt < Ktot; kt += 32) {
        GLDS16(ag0 + kt, lA0);
        GLDS16(ag1 + kt, lA1);
        GLDS16(bg0 + kt, lB0);
        GLDS16(bg1 + kt, lB1);
        __syncthreads();                       // drains vmcnt -> LDS valid
        bf16x8 af[4], bf[4];
        #pragma unroll
        for (int mi = 0; mi < 4; ++mi) af[mi] = *(const bf16x8*)(pa + mi * 16 * 64);
        #pragma unroll
        for (int ni = 0; ni < 4; ++ni) bf[ni] = *(const bf16x8*)(pb + ni * 16 * 64);
        #pragma unroll
        for (int mi = 0; mi < 4; ++mi)
            #pragma unroll
            for (int ni = 0; ni < 4; ++ni)
                acc[mi][ni] = __builtin_amdgcn_mfma_f32_16x16x32_bf16(
                    af[mi], bf[ni], acc[mi][ni], 0, 0, 0);
        __syncthreads();                       // LDS reads done before next stage
    }

    // C/D layout: col = lane&15, row = (lane>>4)*4 + reg  [m89-verified]
    const int col0 = n_base + wn + (lane & 15);
    const int row0 = m_base + wm + (lane >> 4) * 4;
    #pragma unroll
    for (int ni = 0; ni < 4; ++ni) {
        const int col = col0 + ni * 16;
        const float bv = bias[col];
        #pragma unroll
        for (int mi = 0; mi < 4; ++mi) {
            #pragma unroll
            for (int r = 0; r < 4; ++r) {
                out[(long)(row0 + mi * 16 + r) * Otot + col] = acc[mi][ni][r] + bv;
            }
        }
    }
}

extern "C" void kernel_launch(void* const* d_in, const int* in_sizes, int n_in,
                              void* d_out, int out_size, void* d_ws, size_t ws_size,
                              hipStream_t stream) {
    const float* x    = (const float*)d_in[0];
    const int*   tidx = (const int*)  d_in[1];
    const float* temb = (const float*)d_in[2];
    const float* bw   = (const float*)d_in[3];
    const float* bb   = (const float*)d_in[4];
    const float* sw   = (const float*)d_in[5];
    float* out = (float*)d_out;

    __hip_bfloat16* A  = (__hip_bfloat16*)d_ws;                         // 72 MiB
    __hip_bfloat16* Wt = (__hip_bfloat16*)((char*)d_ws + (size_t)Mtot * Ktot * 2);

    prep_A<<<Mtot * 128 / 256, 256, 0, stream>>>(x, tidx, temb, (unsigned int*)A);
    prep_W<<<Otot * 128 / 256, 256, 0, stream>>>(bw, sw, (unsigned int*)Wt);
    gemm_kan<<<dim3(Mtot / 128, Otot / 128), 256, 0, stream>>>(A, Wt, bb, out);
}